// Round 16
// baseline (505.383 us; speedup 1.0000x reference)
//
#include <hip/hip_runtime.h>
#include <hip/hip_bf16.h>

#define PTOT  65536
#define SCALE 0.125f

typedef __attribute__((ext_vector_type(8))) short short8;
typedef __attribute__((ext_vector_type(4))) float f32x4;

__device__ __forceinline__ float leaky(float x, float a) { return x > 0.f ? x : a * x; }

__device__ __forceinline__ unsigned short f2bfbits(float f) {
    __hip_bfloat16 h = __float2bfloat16(f); unsigned short u;
    __builtin_memcpy(&u, &h, 2); return u;
}

__device__ __forceinline__ void gld16(const void* g, void* l) {
    __builtin_amdgcn_global_load_lds(
        (const __attribute__((address_space(1))) unsigned int*)g,
        (__attribute__((address_space(3))) unsigned int*)l, 16, 0, 0);
}

// ---------------------------------------------------------------------------
// MFMA step with A from LDS (128B rows, XOR swizzle slot=c^(row&7)) and
// B read DIRECTLY from global (L2-resident weights -- no LDS staging).
// One K=64 step, wave tile 32x256 -> acc[2][4].
// ---------------------------------------------------------------------------
__device__ __forceinline__ void mfma_gB64(const char* Aseg,
                                          const __hip_bfloat16* __restrict__ Bg, int ldk, int kb,
                                          int l, int wm, int wn, f32x4 acc[2][4])
{
#pragma unroll
    for (int ks = 0; ks < 2; ++ks) {
        short8 af[2], bfr[4];
        const int c = ks * 4 + (l >> 4);
        const int sw = ((c ^ (l & 7)) << 4);
#pragma unroll
        for (int mf = 0; mf < 2; ++mf)
            af[mf] = *(const short8*)(Aseg + (wm * 32 + mf * 16 + (l & 15)) * 128 + sw);
#pragma unroll
        for (int nf = 0; nf < 4; ++nf) {
            const int col = wn * 64 + nf * 16 + (l & 15);
            bfr[nf] = *(const short8*)(Bg + (size_t)col * ldk + kb + c * 8);
        }
#pragma unroll
        for (int mf = 0; mf < 2; ++mf)
#pragma unroll
            for (int nf = 0; nf < 4; ++nf)
                acc[mf][nf] = __builtin_amdgcn_mfma_f32_16x16x32_bf16(af[mf], bfr[nf], acc[mf][nf], 0, 0, 0);
    }
}

// Stage A tile: 64 rows x 64 k (bf16 source, one pass of 512 threads).
__device__ __forceinline__ void stageA64(const __hip_bfloat16* Abf, int pix0, int k0,
                                         char* dst, int w, int l, int cg)
{
    const int row = w * 8 + (l >> 3);
    gld16(Abf + (size_t)(pix0 + row) * 256 + k0 + cg * 8, dst + w * 8 * 128);
}

// ---------------------------------------------------------------------------
// k1 GEMV stage body
// ---------------------------------------------------------------------------
template<int MODE>
__device__ __forceinline__ void k1_body(int bb, int t,
    const float* __restrict__ vin, const float* __restrict__ W,
    const float* __restrict__ g, const float* __restrict__ bv,
    float* __restrict__ vout, float* s0, float (*pr)[32])
{
    const int n = bb >> 3, c0 = (bb & 7) * 32;
    if (t < 256) s0[t] = vin[n * 256 + t];
    __syncthreads();
    const int kp = t >> 5, ci = t & 31, c = c0 + ci;
    float a = 0.f;
#pragma unroll 8
    for (int i = 0; i < 32; ++i) {
        const int k = kp * 32 + i;
        a += s0[k] * W[k * 256 + c];
    }
    pr[kp][ci] = a;
    __syncthreads();
    if (t < 32) {
        float s = 0.f;
#pragma unroll
        for (int q = 0; q < 8; ++q) s += pr[q][t];
        const int cc = c0 + t;
        if constexpr (MODE == 0)      vout[n * 256 + cc] = leaky(s, 0.3f);
        else if constexpr (MODE == 1) vout[n * 256 + cc] = leaky(s * g[cc] + bv[cc], 0.1f);
        else                          vout[n * 256 + cc] = 4096.f * s;
    }
}

template<int MODE>
__global__ __launch_bounds__(256) void k1g(
    const float* __restrict__ vin, const float* __restrict__ W,
    const float* __restrict__ g, const float* __restrict__ bv,
    float* __restrict__ vout)
{
    __shared__ float s0[256];
    __shared__ float pr[8][32];
    k1_body<MODE>(blockIdx.x, threadIdx.x, vin, W, g, bv, vout, s0, pr);
}

// ---------------------------------------------------------------------------
// Prep: blocks 0..1023 WT4 [w][col][k] bf16; 1024..1279 WoutT [col][512];
// 1280..1407 k1 stage0. (Input conversion lives inside kA.)
// ---------------------------------------------------------------------------
__global__ __launch_bounds__(256) void kW_cvt(
    const float* __restrict__ W0, const float* __restrict__ W1,
    const float* __restrict__ W2, const float* __restrict__ W3,
    const float* __restrict__ Wout,
    __hip_bfloat16* __restrict__ WT4, __hip_bfloat16* __restrict__ WoutT,
    const float* __restrict__ style, const float* __restrict__ W_dense,
    float* __restrict__ s1ws)
{
    __shared__ float s0[256];
    __shared__ float pr[8][32];
    const int b = blockIdx.x, t = threadIdx.x;
    if (b < 1024) {
        const int w = b >> 8, c = b & 255;
        const float* W = (w == 0) ? W0 : (w == 1) ? W1 : (w == 2) ? W2 : W3;
        WT4[((size_t)w * 256 + c) * 256 + t] = __float2bfloat16(W[t * 256 + c]);
    } else if (b < 1280) {
        const int c = b - 1024;
        WoutT[(size_t)c * 512 + t]       = __float2bfloat16(Wout[t * 256 + c]);
        WoutT[(size_t)c * 512 + t + 256] = __float2bfloat16(Wout[(t + 256) * 256 + c]);
    } else {
        k1_body<0>(b - 1280, t, style, W_dense, nullptr, nullptr, s1ws, s0, pr);
    }
}

// ---------------------------------------------------------------------------
// kA: merged kc+kp N=512 GEMM + in_bf producer, B DIRECT FROM GLOBAL (L2).
// Per block: 64 pixels. Wave w owns cols w*64.. of [WkcT | WkpT], acc[4][4],
// 8 K-32 steps off resident Afull. ZERO barriers in the K-loop.
// LDS 40KB -> 4 blocks/CU.
// NOTE R14: folding style GEMVs in as an extra block -> 120us straggler. Keep out.
// ---------------------------------------------------------------------------
__global__ __launch_bounds__(512, 6) void kA(
    const float* __restrict__ in, __hip_bfloat16* __restrict__ in_bf,
    const __hip_bfloat16* __restrict__ BkcT, const __hip_bfloat16* __restrict__ BkpT,
    const float* __restrict__ gkc, const float* __restrict__ bkc,
    const float* __restrict__ gkp, const float* __restrict__ bkp,
    const float* __restrict__ W_pos,
    float* __restrict__ partial, float* __restrict__ logits)
{
    __shared__ alignas(16) char smem[40960];
    char* Afull = smem;                        // [4 seg][64 row][128B] = 32KB
    float* wpos_s = (float*)(smem + 32768);    // [256][4] = 4KB
    float* sc     = (float*)(smem + 36864);    // [64][4][4] = 4KB

    const int t = threadIdx.x, l = t & 63, w = t >> 6;   // w = 64-col group
    const int pix0 = blockIdx.x * 64;

    for (int e = t; e < 1024; e += 512) wpos_s[e] = W_pos[1024 + e]; // rows 256..511

    // stage full A tile from fp32 (row=t>>3, chunk c=t&7); also emit in_bf
    {
        const int row = t >> 3, c = t & 7;
#pragma unroll
        for (int seg = 0; seg < 4; ++seg) {
            const float* p = in + (size_t)(pix0 + row) * 256 + seg * 64 + c * 8;
            const float4 x0 = *(const float4*)p, x1 = *(const float4*)(p + 4);
            short8 v;
            v[0]=(short)f2bfbits(x0.x); v[1]=(short)f2bfbits(x0.y); v[2]=(short)f2bfbits(x0.z); v[3]=(short)f2bfbits(x0.w);
            v[4]=(short)f2bfbits(x1.x); v[5]=(short)f2bfbits(x1.y); v[6]=(short)f2bfbits(x1.z); v[7]=(short)f2bfbits(x1.w);
            *(short8*)(Afull + seg * 8192 + row * 128 + ((c ^ (row & 7)) << 4)) = v;
            *(short8*)(in_bf + (size_t)(pix0 + row) * 256 + seg * 64 + c * 8) = v;
        }
    }
    __syncthreads();                            // Afull visible to all waves

    // per-wave B base (cols w*64.. of kc for w<4, of kp for w>=4)
    const __hip_bfloat16* Bw = (w < 4) ? (BkcT + (size_t)(w * 64) * 256)
                                       : (BkpT + (size_t)((w - 4) * 64) * 256);

    f32x4 acc[4][4];
#pragma unroll
    for (int i = 0; i < 4; ++i)
#pragma unroll
        for (int j = 0; j < 4; ++j) acc[i][j] = (f32x4)0.f;

    for (int s = 0; s < 8; ++s) {               // K=32 per step, NO barriers
        const int c8 = (s & 1) * 4 + (l >> 4);
        const char* Aseg = Afull + (s >> 1) * 8192;
        short8 af[4], bfr[4];
#pragma unroll
        for (int mf = 0; mf < 4; ++mf) {
            const int row = mf * 16 + (l & 15);
            af[mf] = *(const short8*)(Aseg + row * 128 + ((c8 ^ (row & 7)) << 4));
        }
#pragma unroll
        for (int nf = 0; nf < 4; ++nf)
            bfr[nf] = *(const short8*)(Bw + (size_t)(nf * 16 + (l & 15)) * 256 + s * 32 + (l >> 4) * 8);
#pragma unroll
        for (int mf = 0; mf < 4; ++mf)
#pragma unroll
            for (int nf = 0; nf < 4; ++nf)
                acc[mf][nf] = __builtin_amdgcn_mfma_f32_16x16x32_bf16(af[mf], bfr[nf], acc[mf][nf], 0, 0, 0);
    }

    if (w < 4) {
        // ---- kc epilogue: column sums over all 64 rows (in-wave) ----
#pragma unroll
        for (int nf = 0; nf < 4; ++nf) {
            const int col = w * 64 + nf * 16 + (l & 15);
            const float g = gkc[col], bb = bkc[col];
            float cs = 0.f;
#pragma unroll
            for (int mf = 0; mf < 4; ++mf)
#pragma unroll
                for (int r = 0; r < 4; ++r) cs += leaky(acc[mf][nf][r] * g + bb, 0.1f);
            cs += __shfl_xor(cs, 16);
            cs += __shfl_xor(cs, 32);
            if (l < 16) partial[(size_t)blockIdx.x * 256 + col] = cs;
        }
    } else {
        // ---- kp epilogue: pos logits ----
#pragma unroll
        for (int mf = 0; mf < 4; ++mf)
#pragma unroll
            for (int r = 0; r < 4; ++r) {
                const int row = mf * 16 + (l >> 4) * 4 + r;
                float pm0 = 0.f, pm1 = 0.f, pm2 = 0.f, pm3 = 0.f;
#pragma unroll
                for (int nf = 0; nf < 4; ++nf) {
                    const int kcol = (w - 4) * 64 + nf * 16 + (l & 15);
                    const float g = gkp[kcol], bb = bkp[kcol];
                    const float v = leaky(acc[mf][nf][r] * g + bb, 0.1f);
                    pm0 += v * wpos_s[kcol * 4 + 0];
                    pm1 += v * wpos_s[kcol * 4 + 1];
                    pm2 += v * wpos_s[kcol * 4 + 2];
                    pm3 += v * wpos_s[kcol * 4 + 3];
                }
#pragma unroll
                for (int mask = 1; mask <= 8; mask <<= 1) {
                    pm0 += __shfl_xor(pm0, mask);
                    pm1 += __shfl_xor(pm1, mask);
                    pm2 += __shfl_xor(pm2, mask);
                    pm3 += __shfl_xor(pm3, mask);
                }
                if ((l & 15) == 0) {
                    float* sp = &sc[row * 16 + (w - 4)];
                    sp[0] = pm0; sp[4] = pm1; sp[8] = pm2; sp[12] = pm3;
                }
            }
    }
    __syncthreads();
    if (t < 256) {
        const int row = t >> 2, m = t & 3;
        const float sum = sc[row * 16 + m * 4 + 0] + sc[row * 16 + m * 4 + 1]
                        + sc[row * 16 + m * 4 + 2] + sc[row * 16 + m * 4 + 3];
        logits[(size_t)(pix0 + row) * 4 + m] = SCALE * sum;
    }
}

// ---------------------------------------------------------------------------
// Fused softmax kernel: blocks 0..15 channel softmax; 16..79 position softmax.
// ---------------------------------------------------------------------------
__global__ __launch_bounds__(256) void k2bc(
    const float* __restrict__ partial,   // [1024][256]
    const float* __restrict__ acq, const float* __restrict__ W_ch,
    float* __restrict__ a_c, float* __restrict__ lg)
{
    const int t = threadIdx.x;
    if (blockIdx.x < 16) {
        __shared__ float ks[256], lgs[256];
        const int n = blockIdx.x;
        float s = 0.f;
        for (int tt = 0; tt < 64; ++tt) s += partial[(size_t)(n * 64 + tt) * 256 + t];
        ks[t] = s;
        __syncthreads();
        float bot = 0.f;
        for (int d = 0; d < 256; ++d) bot += ks[d] * W_ch[(256 + d) * 256 + t];
        const float L = SCALE * (acq[n * 256 + t] + bot);
        lgs[t] = L;
        __syncthreads();
        const int nh = t & 3;
        float mx = -1e30f;
        for (int i = 0; i < 64; ++i) mx = fmaxf(mx, lgs[i * 4 + nh]);
        float sum = 0.f;
        for (int i = 0; i < 64; ++i) sum += __expf(lgs[i * 4 + nh] - mx);
        a_c[n * 256 + t] = __expf(L - mx) / sum;
    } else {
        __shared__ float r[256];
        const int bb = blockIdx.x - 16;
        const int n = bb >> 2, m = bb & 3;
        const int base = n * 4096;
        float v[16];
        float mx = -1e30f;
#pragma unroll
        for (int i = 0; i < 16; ++i) {
            v[i] = lg[(size_t)(base + i * 256 + t) * 4 + m];
            mx = fmaxf(mx, v[i]);
        }
        r[t] = mx; __syncthreads();
        for (int s = 128; s > 0; s >>= 1) { if (t < s) r[t] = fmaxf(r[t], r[t + s]); __syncthreads(); }
        mx = r[0]; __syncthreads();
        float sum = 0.f;
#pragma unroll
        for (int i = 0; i < 16; ++i) { v[i] = __expf(v[i] - mx); sum += v[i]; }
        r[t] = sum; __syncthreads();
        for (int s = 128; s > 0; s >>= 1) { if (t < s) r[t] += r[t + s]; __syncthreads(); }
        const float rinv = 1.f / r[0];
#pragma unroll
        for (int i = 0; i < 16; ++i) lg[(size_t)(base + i * 256 + t) * 4 + m] = v[i] * rinv;
    }
}

// ---------------------------------------------------------------------------
// kB: fused v-recompute + attention-scale + output GEMM, B DIRECT FROM GLOBAL.
// Per block 64 pixels.
//   phase V: per K-step {sync; stage A; sync; mfma_c(Bvc global); mfma_p(Bvp)}
//   epilogue-c -> A2; sync; Gc: 4 barrier-free steps (A2 LDS + WoutT global)
//   sync; epilogue-p -> A2; sync; Gp: 4 barrier-free steps
// Barriers 34 -> 11. LDS 42KB -> 3 blocks/CU.
// NOTE: R8 (K=32 dbuf), R12 (merged window), R9 (LDS-out epilogue) regressed.
// ---------------------------------------------------------------------------
__global__ __launch_bounds__(512, 6) void kB(
    const __hip_bfloat16* __restrict__ Abf,
    const __hip_bfloat16* __restrict__ BvcT, const __hip_bfloat16* __restrict__ BvpT,
    const __hip_bfloat16* __restrict__ WoutT,
    const float* __restrict__ gvc, const float* __restrict__ bvc,
    const float* __restrict__ gvp, const float* __restrict__ bvp,
    const float* __restrict__ a_c, const float* __restrict__ apos,
    const float* __restrict__ g_out, const float* __restrict__ b_out,
    float* __restrict__ outp)
{
    __shared__ alignas(16) char smem[43008];
    char* As   = smem;                        // [64 row][128B] = 8KB
    char* A2   = smem + 8192;                 // [4 seg][64 row][128B] = 32KB
    float* ac_s = (float*)(smem + 40960);     // [256]
    float* ap_s = (float*)(smem + 41984);     // [64][4]

    const int t = threadIdx.x, l = t & 63, w = t >> 6;
    const int wm = w >> 2, wn = w & 3;
    const int pix0 = blockIdx.x * 64;
    const int n = pix0 >> 12;
    const int cg = (l & 7) ^ ((l >> 3) & 7);

    if (t < 256) {
        ac_s[t] = a_c[n * 256 + t];
        ap_s[t] = apos[(size_t)pix0 * 4 + t];
    }

    f32x4 acc1c[2][4], acc1p[2][4], acc2[2][4];
#pragma unroll
    for (int i = 0; i < 2; ++i)
#pragma unroll
        for (int j = 0; j < 4; ++j) {
            acc1c[i][j] = (f32x4)0.f;
            acc1p[i][j] = (f32x4)0.f;
            acc2[i][j]  = (f32x4)0.f;
        }

    // ---- phase V: A staged once per step, both halves' B from global ----
    for (int s = 0; s < 4; ++s) {
        __syncthreads();                       // prev step's As reads done (s=0: ac_s/ap_s)
        stageA64(Abf, pix0, s * 64, As, w, l, cg);
        __syncthreads();                       // As visible
        mfma_gB64(As, BvcT, 256, s * 64, l, wm, wn, acc1c);
        mfma_gB64(As, BvpT, 256, s * 64, l, wm, wn, acc1p);
    }

    // ---- epilogue c: BN+leaky, a_c scale, bf16 -> A2 (swizzled) ----
#pragma unroll
    for (int nf = 0; nf < 4; ++nf) {
        const int col = wn * 64 + nf * 16 + (l & 15);
        const float g = gvc[col], bb = bvc[col];
        const int c2 = (col & 63) >> 3, cb = (col & 7) * 2;
        const float sc_c = ac_s[col];
#pragma unroll
        for (int mf = 0; mf < 2; ++mf)
#pragma unroll
            for (int r = 0; r < 4; ++r) {
                const int row = wm * 32 + mf * 16 + (l >> 4) * 4 + r;
                float v = leaky(acc1c[mf][nf][r] * g + bb, 0.1f) * sc_c;
                *(unsigned short*)(A2 + wn * 8192 + row * 128
                                   + ((c2 ^ (row & 7)) << 4) + cb) = f2bfbits(v);
            }
    }
    __syncthreads();                           // A2(c) visible
    // ---- phase Gc: 4 barrier-free steps, WoutT from global ----
#pragma unroll
    for (int s = 0; s < 4; ++s)
        mfma_gB64(A2 + s * 8192, WoutT, 512, s * 64, l, wm, wn, acc2);
    __syncthreads();                           // all A2(c) reads done
    // ---- epilogue p: BN+leaky, a_p scale, bf16 -> A2 (overwrite) ----
#pragma unroll
    for (int nf = 0; nf < 4; ++nf) {
        const int col = wn * 64 + nf * 16 + (l & 15);
        const float g = gvp[col], bb = bvp[col];
        const int c2 = (col & 63) >> 3, cb = (col & 7) * 2;
#pragma unroll
        for (int mf = 0; mf < 2; ++mf)
#pragma unroll
            for (int r = 0; r < 4; ++r) {
                const int row = wm * 32 + mf * 16 + (l >> 4) * 4 + r;
                float v = leaky(acc1p[mf][nf][r] * g + bb, 0.1f) * ap_s[row * 4 + wn];
                *(unsigned short*)(A2 + wn * 8192 + row * 128
                                   + ((c2 ^ (row & 7)) << 4) + cb) = f2bfbits(v);
            }
    }
    __syncthreads();                           // A2(p) visible
    // ---- phase Gp: 4 barrier-free steps ----
#pragma unroll
    for (int s = 0; s < 4; ++s)
        mfma_gB64(A2 + s * 8192, WoutT, 512, 256 + s * 64, l, wm, wn, acc2);

    // ---- final epilogue: direct stores ----
#pragma unroll
    for (int nf = 0; nf < 4; ++nf) {
        const int col = wn * 64 + nf * 16 + (l & 15);
        const float g = g_out[col], bb = b_out[col];
#pragma unroll
        for (int mf = 0; mf < 2; ++mf)
#pragma unroll
            for (int r = 0; r < 4; ++r) {
                const int p = pix0 + wm * 32 + mf * 16 + (l >> 4) * 4 + r;
                outp[(size_t)p * 256 + col] = leaky(acc2[mf][nf][r] * g + bb, 0.1f);
            }
    }
}

// ---------------------------------------------------------------------------
// Launch
// ---------------------------------------------------------------------------
extern "C" void kernel_launch(void* const* d_in, const int* in_sizes, int n_in,
                              void* d_out, int out_size, void* d_ws, size_t ws_size,
                              hipStream_t stream)
{
    const float* inputs  = (const float*)d_in[0];
    const float* style   = (const float*)d_in[1];
    const float* W_dense = (const float*)d_in[2];
    const float* Wq_c = (const float*)d_in[3];
    const float* gq_c = (const float*)d_in[4];
    const float* bq_c = (const float*)d_in[5];
    const float* Wk_c = (const float*)d_in[6];
    const float* gk_c = (const float*)d_in[7];
    const float* bk_c = (const float*)d_in[8];
    const float* Wv_c = (const float*)d_in[9];
    const float* gv_c = (const float*)d_in[10];
    const float* bv_c = (const float*)d_in[11];
    // Wq_p/gq_p/bq_p (12..14) unused: qp-part is softmax-invariant
    const float* Wk_p = (const float*)d_in[15];
    const float* gk_p = (const float*)d_in[16];
    const float* bk_p = (const float*)d_in[17];
    const float* Wv_p = (const float*)d_in[18];
    const float* gv_p = (const float*)d_in[19];
    const float* bv_p = (const float*)d_in[20];
    const float* W_ch  = (const float*)d_in[21];
    const float* W_pos = (const float*)d_in[22];
    const float* W_out = (const float*)d_in[23];
    const float* g_out = (const float*)d_in[24];
    const float* b_out = (const float*)d_in[25];

    float* ws = (float*)d_ws;
    float* s1ws    = ws;                  //      4096
    float* qcws    = ws + 4096;           //      4096
    float* acq     = ws + 8192;           //      4096
    float* a_c     = ws + 12288;          //      4096
    float* partial = ws + 16384;          //    262144 (1024 x 256)
    float* logits  = ws + 278528;         //    262144 (65536 x 4) -> a_p in place
    __hip_bfloat16* in_bf = (__hip_bfloat16*)(ws + 540672);   // 65536x256 bf16 = 8388608 float-slots
    __hip_bfloat16* WT4   = (__hip_bfloat16*)(ws + 8929280);  // 4x256x256 bf16 [col][k]
    __hip_bfloat16* WoutT = (__hip_bfloat16*)(ws + 9060352);  // 256x512 bf16 [col][k]
    // total 9,125,888 floats = 36.5 MB

    kW_cvt<<<1408, 256, 0, stream>>>(Wk_c, Wv_c, Wk_p, Wv_p, W_out,
                                     WT4, WoutT, style, W_dense, s1ws);
    k1g<1><<<128, 256, 0, stream>>>(s1ws, Wq_c, gq_c, bq_c, qcws);
    k1g<2><<<128, 256, 0, stream>>>(qcws, W_ch, nullptr, nullptr, acq);

    kA<<<1024, 512, 0, stream>>>(inputs, in_bf, WT4, WT4 + 2 * 65536,
                                 gk_c, bk_c, gk_p, bk_p, W_pos, partial, logits);

    k2bc<<<80, 256, 0, stream>>>(partial, acq, W_ch, a_c, logits);

    kB<<<1024, 512, 0, stream>>>(in_bf, WT4 + 65536, WT4 + 3 * 65536, WoutT,
                                 gv_c, bv_c, gv_p, bv_p, a_c, logits,
                                 g_out, b_out, (float*)d_out);
}

// Round 17
// 230.372 us; speedup vs baseline: 2.1938x; 2.1938x over previous
//
#include <hip/hip_runtime.h>
#include <hip/hip_bf16.h>

#define PTOT  65536
#define SCALE 0.125f

typedef __attribute__((ext_vector_type(8))) short short8;
typedef __attribute__((ext_vector_type(4))) float f32x4;

__device__ __forceinline__ float leaky(float x, float a) { return x > 0.f ? x : a * x; }

__device__ __forceinline__ unsigned short f2bfbits(float f) {
    __hip_bfloat16 h = __float2bfloat16(f); unsigned short u;
    __builtin_memcpy(&u, &h, 2); return u;
}

__device__ __forceinline__ void gld16(const void* g, void* l) {
    __builtin_amdgcn_global_load_lds(
        (const __attribute__((address_space(1))) unsigned int*)g,
        (__attribute__((address_space(3))) unsigned int*)l, 16, 0, 0);
}

// ---------------------------------------------------------------------------
// MFMA step with A from LDS (128B rows, XOR swizzle slot=c^(row&7)) and
// B read DIRECTLY from global (L2-resident weights -- no LDS staging).
// One K=64 step, wave tile 32x256 -> acc[2][4].
// ---------------------------------------------------------------------------
__device__ __forceinline__ void mfma_gB64(const char* Aseg,
                                          const __hip_bfloat16* __restrict__ Bg, int ldk, int kb,
                                          int l, int wm, int wn, f32x4 acc[2][4])
{
#pragma unroll
    for (int ks = 0; ks < 2; ++ks) {
        short8 af[2], bfr[4];
        const int c = ks * 4 + (l >> 4);
        const int sw = ((c ^ (l & 7)) << 4);
#pragma unroll
        for (int mf = 0; mf < 2; ++mf)
            af[mf] = *(const short8*)(Aseg + (wm * 32 + mf * 16 + (l & 15)) * 128 + sw);
#pragma unroll
        for (int nf = 0; nf < 4; ++nf) {
            const int col = wn * 64 + nf * 16 + (l & 15);
            bfr[nf] = *(const short8*)(Bg + (size_t)col * ldk + kb + c * 8);
        }
#pragma unroll
        for (int mf = 0; mf < 2; ++mf)
#pragma unroll
            for (int nf = 0; nf < 4; ++nf)
                acc[mf][nf] = __builtin_amdgcn_mfma_f32_16x16x32_bf16(af[mf], bfr[nf], acc[mf][nf], 0, 0, 0);
    }
}

// Stage A tile: 64 rows x 64 k (bf16 source, one pass of 512 threads).
__device__ __forceinline__ void stageA64(const __hip_bfloat16* Abf, int pix0, int k0,
                                         char* dst, int w, int l, int cg)
{
    const int row = w * 8 + (l >> 3);
    gld16(Abf + (size_t)(pix0 + row) * 256 + k0 + cg * 8, dst + w * 8 * 128);
}

// ---------------------------------------------------------------------------
// k1 GEMV stage body
// ---------------------------------------------------------------------------
template<int MODE>
__device__ __forceinline__ void k1_body(int bb, int t,
    const float* __restrict__ vin, const float* __restrict__ W,
    const float* __restrict__ g, const float* __restrict__ bv,
    float* __restrict__ vout, float* s0, float (*pr)[32])
{
    const int n = bb >> 3, c0 = (bb & 7) * 32;
    if (t < 256) s0[t] = vin[n * 256 + t];
    __syncthreads();
    const int kp = t >> 5, ci = t & 31, c = c0 + ci;
    float a = 0.f;
#pragma unroll 8
    for (int i = 0; i < 32; ++i) {
        const int k = kp * 32 + i;
        a += s0[k] * W[k * 256 + c];
    }
    pr[kp][ci] = a;
    __syncthreads();
    if (t < 32) {
        float s = 0.f;
#pragma unroll
        for (int q = 0; q < 8; ++q) s += pr[q][t];
        const int cc = c0 + t;
        if constexpr (MODE == 0)      vout[n * 256 + cc] = leaky(s, 0.3f);
        else if constexpr (MODE == 1) vout[n * 256 + cc] = leaky(s * g[cc] + bv[cc], 0.1f);
        else                          vout[n * 256 + cc] = 4096.f * s;
    }
}

template<int MODE>
__global__ __launch_bounds__(256) void k1g(
    const float* __restrict__ vin, const float* __restrict__ W,
    const float* __restrict__ g, const float* __restrict__ bv,
    float* __restrict__ vout)
{
    __shared__ float s0[256];
    __shared__ float pr[8][32];
    k1_body<MODE>(blockIdx.x, threadIdx.x, vin, W, g, bv, vout, s0, pr);
}

// ---------------------------------------------------------------------------
// Prep: blocks 0..1023 WT4 [w][col][k] bf16; 1024..1279 WoutT [col][512];
// 1280..1407 k1 stage0. (Input conversion lives inside kA.)
// ---------------------------------------------------------------------------
__global__ __launch_bounds__(256) void kW_cvt(
    const float* __restrict__ W0, const float* __restrict__ W1,
    const float* __restrict__ W2, const float* __restrict__ W3,
    const float* __restrict__ Wout,
    __hip_bfloat16* __restrict__ WT4, __hip_bfloat16* __restrict__ WoutT,
    const float* __restrict__ style, const float* __restrict__ W_dense,
    float* __restrict__ s1ws)
{
    __shared__ float s0[256];
    __shared__ float pr[8][32];
    const int b = blockIdx.x, t = threadIdx.x;
    if (b < 1024) {
        const int w = b >> 8, c = b & 255;
        const float* W = (w == 0) ? W0 : (w == 1) ? W1 : (w == 2) ? W2 : W3;
        WT4[((size_t)w * 256 + c) * 256 + t] = __float2bfloat16(W[t * 256 + c]);
    } else if (b < 1280) {
        const int c = b - 1024;
        WoutT[(size_t)c * 512 + t]       = __float2bfloat16(Wout[t * 256 + c]);
        WoutT[(size_t)c * 512 + t + 256] = __float2bfloat16(Wout[(t + 256) * 256 + c]);
    } else {
        k1_body<0>(b - 1280, t, style, W_dense, nullptr, nullptr, s1ws, s0, pr);
    }
}

// ---------------------------------------------------------------------------
// kA: merged kc+kp N=512 GEMM + in_bf producer, B DIRECT FROM GLOBAL (L2).
// Per block: 64 pixels. Wave w owns cols w*64.. of [WkcT | WkpT], acc[4][4],
// 8 K-32 steps off resident Afull. ZERO barriers in the K-loop.
// LDS 40KB. __launch_bounds__(512,4): R16's (512,6) squeezed the unified
// VGPR/AGPR budget and spilled accumulators to scratch (VGPR 40, 705MB writes).
// ---------------------------------------------------------------------------
__global__ __launch_bounds__(512, 4) void kA(
    const float* __restrict__ in, __hip_bfloat16* __restrict__ in_bf,
    const __hip_bfloat16* __restrict__ BkcT, const __hip_bfloat16* __restrict__ BkpT,
    const float* __restrict__ gkc, const float* __restrict__ bkc,
    const float* __restrict__ gkp, const float* __restrict__ bkp,
    const float* __restrict__ W_pos,
    float* __restrict__ partial, float* __restrict__ logits)
{
    __shared__ alignas(16) char smem[40960];
    char* Afull = smem;                        // [4 seg][64 row][128B] = 32KB
    float* wpos_s = (float*)(smem + 32768);    // [256][4] = 4KB
    float* sc     = (float*)(smem + 36864);    // [64][4][4] = 4KB

    const int t = threadIdx.x, l = t & 63, w = t >> 6;   // w = 64-col group
    const int pix0 = blockIdx.x * 64;

    for (int e = t; e < 1024; e += 512) wpos_s[e] = W_pos[1024 + e]; // rows 256..511

    // stage full A tile from fp32 (row=t>>3, chunk c=t&7); also emit in_bf
    {
        const int row = t >> 3, c = t & 7;
#pragma unroll
        for (int seg = 0; seg < 4; ++seg) {
            const float* p = in + (size_t)(pix0 + row) * 256 + seg * 64 + c * 8;
            const float4 x0 = *(const float4*)p, x1 = *(const float4*)(p + 4);
            short8 v;
            v[0]=(short)f2bfbits(x0.x); v[1]=(short)f2bfbits(x0.y); v[2]=(short)f2bfbits(x0.z); v[3]=(short)f2bfbits(x0.w);
            v[4]=(short)f2bfbits(x1.x); v[5]=(short)f2bfbits(x1.y); v[6]=(short)f2bfbits(x1.z); v[7]=(short)f2bfbits(x1.w);
            *(short8*)(Afull + seg * 8192 + row * 128 + ((c ^ (row & 7)) << 4)) = v;
            *(short8*)(in_bf + (size_t)(pix0 + row) * 256 + seg * 64 + c * 8) = v;
        }
    }
    __syncthreads();                            // Afull visible to all waves

    // per-wave B base (cols w*64.. of kc for w<4, of kp for w>=4)
    const __hip_bfloat16* Bw = (w < 4) ? (BkcT + (size_t)(w * 64) * 256)
                                       : (BkpT + (size_t)((w - 4) * 64) * 256);

    f32x4 acc[4][4];
#pragma unroll
    for (int i = 0; i < 4; ++i)
#pragma unroll
        for (int j = 0; j < 4; ++j) acc[i][j] = (f32x4)0.f;

    for (int s = 0; s < 8; ++s) {               // K=32 per step, NO barriers
        const int c8 = (s & 1) * 4 + (l >> 4);
        const char* Aseg = Afull + (s >> 1) * 8192;
        short8 af[4], bfr[4];
#pragma unroll
        for (int mf = 0; mf < 4; ++mf) {
            const int row = mf * 16 + (l & 15);
            af[mf] = *(const short8*)(Aseg + row * 128 + ((c8 ^ (row & 7)) << 4));
        }
#pragma unroll
        for (int nf = 0; nf < 4; ++nf)
            bfr[nf] = *(const short8*)(Bw + (size_t)(nf * 16 + (l & 15)) * 256 + s * 32 + (l >> 4) * 8);
#pragma unroll
        for (int mf = 0; mf < 4; ++mf)
#pragma unroll
            for (int nf = 0; nf < 4; ++nf)
                acc[mf][nf] = __builtin_amdgcn_mfma_f32_16x16x32_bf16(af[mf], bfr[nf], acc[mf][nf], 0, 0, 0);
    }

    if (w < 4) {
        // ---- kc epilogue: column sums over all 64 rows (in-wave) ----
#pragma unroll
        for (int nf = 0; nf < 4; ++nf) {
            const int col = w * 64 + nf * 16 + (l & 15);
            const float g = gkc[col], bb = bkc[col];
            float cs = 0.f;
#pragma unroll
            for (int mf = 0; mf < 4; ++mf)
#pragma unroll
                for (int r = 0; r < 4; ++r) cs += leaky(acc[mf][nf][r] * g + bb, 0.1f);
            cs += __shfl_xor(cs, 16);
            cs += __shfl_xor(cs, 32);
            if (l < 16) partial[(size_t)blockIdx.x * 256 + col] = cs;
        }
    } else {
        // ---- kp epilogue: pos logits ----
#pragma unroll
        for (int mf = 0; mf < 4; ++mf)
#pragma unroll
            for (int r = 0; r < 4; ++r) {
                const int row = mf * 16 + (l >> 4) * 4 + r;
                float pm0 = 0.f, pm1 = 0.f, pm2 = 0.f, pm3 = 0.f;
#pragma unroll
                for (int nf = 0; nf < 4; ++nf) {
                    const int kcol = (w - 4) * 64 + nf * 16 + (l & 15);
                    const float g = gkp[kcol], bb = bkp[kcol];
                    const float v = leaky(acc[mf][nf][r] * g + bb, 0.1f);
                    pm0 += v * wpos_s[kcol * 4 + 0];
                    pm1 += v * wpos_s[kcol * 4 + 1];
                    pm2 += v * wpos_s[kcol * 4 + 2];
                    pm3 += v * wpos_s[kcol * 4 + 3];
                }
#pragma unroll
                for (int mask = 1; mask <= 8; mask <<= 1) {
                    pm0 += __shfl_xor(pm0, mask);
                    pm1 += __shfl_xor(pm1, mask);
                    pm2 += __shfl_xor(pm2, mask);
                    pm3 += __shfl_xor(pm3, mask);
                }
                if ((l & 15) == 0) {
                    float* sp = &sc[row * 16 + (w - 4)];
                    sp[0] = pm0; sp[4] = pm1; sp[8] = pm2; sp[12] = pm3;
                }
            }
    }
    __syncthreads();
    if (t < 256) {
        const int row = t >> 2, m = t & 3;
        const float sum = sc[row * 16 + m * 4 + 0] + sc[row * 16 + m * 4 + 1]
                        + sc[row * 16 + m * 4 + 2] + sc[row * 16 + m * 4 + 3];
        logits[(size_t)(pix0 + row) * 4 + m] = SCALE * sum;
    }
}

// ---------------------------------------------------------------------------
// Fused softmax kernel: blocks 0..15 channel softmax; 16..79 position softmax.
// ---------------------------------------------------------------------------
__global__ __launch_bounds__(256) void k2bc(
    const float* __restrict__ partial,   // [1024][256]
    const float* __restrict__ acq, const float* __restrict__ W_ch,
    float* __restrict__ a_c, float* __restrict__ lg)
{
    const int t = threadIdx.x;
    if (blockIdx.x < 16) {
        __shared__ float ks[256], lgs[256];
        const int n = blockIdx.x;
        float s = 0.f;
        for (int tt = 0; tt < 64; ++tt) s += partial[(size_t)(n * 64 + tt) * 256 + t];
        ks[t] = s;
        __syncthreads();
        float bot = 0.f;
        for (int d = 0; d < 256; ++d) bot += ks[d] * W_ch[(256 + d) * 256 + t];
        const float L = SCALE * (acq[n * 256 + t] + bot);
        lgs[t] = L;
        __syncthreads();
        const int nh = t & 3;
        float mx = -1e30f;
        for (int i = 0; i < 64; ++i) mx = fmaxf(mx, lgs[i * 4 + nh]);
        float sum = 0.f;
        for (int i = 0; i < 64; ++i) sum += __expf(lgs[i * 4 + nh] - mx);
        a_c[n * 256 + t] = __expf(L - mx) / sum;
    } else {
        __shared__ float r[256];
        const int bb = blockIdx.x - 16;
        const int n = bb >> 2, m = bb & 3;
        const int base = n * 4096;
        float v[16];
        float mx = -1e30f;
#pragma unroll
        for (int i = 0; i < 16; ++i) {
            v[i] = lg[(size_t)(base + i * 256 + t) * 4 + m];
            mx = fmaxf(mx, v[i]);
        }
        r[t] = mx; __syncthreads();
        for (int s = 128; s > 0; s >>= 1) { if (t < s) r[t] = fmaxf(r[t], r[t + s]); __syncthreads(); }
        mx = r[0]; __syncthreads();
        float sum = 0.f;
#pragma unroll
        for (int i = 0; i < 16; ++i) { v[i] = __expf(v[i] - mx); sum += v[i]; }
        r[t] = sum; __syncthreads();
        for (int s = 128; s > 0; s >>= 1) { if (t < s) r[t] += r[t + s]; __syncthreads(); }
        const float rinv = 1.f / r[0];
#pragma unroll
        for (int i = 0; i < 16; ++i) lg[(size_t)(base + i * 256 + t) * 4 + m] = v[i] * rinv;
    }
}

// ---------------------------------------------------------------------------
// kB: fused v-recompute + attention-scale + output GEMM, B DIRECT FROM GLOBAL.
// Per block 64 pixels.
//   phase V: per K-step {sync; stage A; sync; mfma_c(Bvc global); mfma_p(Bvp)}
//   epilogue-c -> A2; sync; Gc: 4 barrier-free steps (A2 LDS + WoutT global)
//   sync; epilogue-p -> A2; sync; Gp: 4 barrier-free steps
// Barriers 34 -> 11. LDS 42KB. __launch_bounds__(512,4): see kA note (R16's
// (512,6) caused accumulator spill -> 705MB scratch writes, 320us).
// ---------------------------------------------------------------------------
__global__ __launch_bounds__(512, 4) void kB(
    const __hip_bfloat16* __restrict__ Abf,
    const __hip_bfloat16* __restrict__ BvcT, const __hip_bfloat16* __restrict__ BvpT,
    const __hip_bfloat16* __restrict__ WoutT,
    const float* __restrict__ gvc, const float* __restrict__ bvc,
    const float* __restrict__ gvp, const float* __restrict__ bvp,
    const float* __restrict__ a_c, const float* __restrict__ apos,
    const float* __restrict__ g_out, const float* __restrict__ b_out,
    float* __restrict__ outp)
{
    __shared__ alignas(16) char smem[43008];
    char* As   = smem;                        // [64 row][128B] = 8KB
    char* A2   = smem + 8192;                 // [4 seg][64 row][128B] = 32KB
    float* ac_s = (float*)(smem + 40960);     // [256]
    float* ap_s = (float*)(smem + 41984);     // [64][4]

    const int t = threadIdx.x, l = t & 63, w = t >> 6;
    const int wm = w >> 2, wn = w & 3;
    const int pix0 = blockIdx.x * 64;
    const int n = pix0 >> 12;
    const int cg = (l & 7) ^ ((l >> 3) & 7);

    if (t < 256) {
        ac_s[t] = a_c[n * 256 + t];
        ap_s[t] = apos[(size_t)pix0 * 4 + t];
    }

    f32x4 acc1c[2][4], acc1p[2][4], acc2[2][4];
#pragma unroll
    for (int i = 0; i < 2; ++i)
#pragma unroll
        for (int j = 0; j < 4; ++j) {
            acc1c[i][j] = (f32x4)0.f;
            acc1p[i][j] = (f32x4)0.f;
            acc2[i][j]  = (f32x4)0.f;
        }

    // ---- phase V: A staged once per step, both halves' B from global ----
    for (int s = 0; s < 4; ++s) {
        __syncthreads();                       // prev step's As reads done (s=0: ac_s/ap_s)
        stageA64(Abf, pix0, s * 64, As, w, l, cg);
        __syncthreads();                       // As visible
        mfma_gB64(As, BvcT, 256, s * 64, l, wm, wn, acc1c);
        mfma_gB64(As, BvpT, 256, s * 64, l, wm, wn, acc1p);
    }

    // ---- epilogue c: BN+leaky, a_c scale, bf16 -> A2 (swizzled) ----
#pragma unroll
    for (int nf = 0; nf < 4; ++nf) {
        const int col = wn * 64 + nf * 16 + (l & 15);
        const float g = gvc[col], bb = bvc[col];
        const int c2 = (col & 63) >> 3, cb = (col & 7) * 2;
        const float sc_c = ac_s[col];
#pragma unroll
        for (int mf = 0; mf < 2; ++mf)
#pragma unroll
            for (int r = 0; r < 4; ++r) {
                const int row = wm * 32 + mf * 16 + (l >> 4) * 4 + r;
                float v = leaky(acc1c[mf][nf][r] * g + bb, 0.1f) * sc_c;
                *(unsigned short*)(A2 + wn * 8192 + row * 128
                                   + ((c2 ^ (row & 7)) << 4) + cb) = f2bfbits(v);
            }
    }
    __syncthreads();                           // A2(c) visible
    // ---- phase Gc: 4 barrier-free steps, WoutT from global ----
#pragma unroll
    for (int s = 0; s < 4; ++s)
        mfma_gB64(A2 + s * 8192, WoutT, 512, s * 64, l, wm, wn, acc2);
    __syncthreads();                           // all A2(c) reads done
    // ---- epilogue p: BN+leaky, a_p scale, bf16 -> A2 (overwrite) ----
#pragma unroll
    for (int nf = 0; nf < 4; ++nf) {
        const int col = wn * 64 + nf * 16 + (l & 15);
        const float g = gvp[col], bb = bvp[col];
        const int c2 = (col & 63) >> 3, cb = (col & 7) * 2;
#pragma unroll
        for (int mf = 0; mf < 2; ++mf)
#pragma unroll
            for (int r = 0; r < 4; ++r) {
                const int row = wm * 32 + mf * 16 + (l >> 4) * 4 + r;
                float v = leaky(acc1p[mf][nf][r] * g + bb, 0.1f) * ap_s[row * 4 + wn];
                *(unsigned short*)(A2 + wn * 8192 + row * 128
                                   + ((c2 ^ (row & 7)) << 4) + cb) = f2bfbits(v);
            }
    }
    __syncthreads();                           // A2(p) visible
    // ---- phase Gp: 4 barrier-free steps ----
#pragma unroll
    for (int s = 0; s < 4; ++s)
        mfma_gB64(A2 + s * 8192, WoutT, 512, 256 + s * 64, l, wm, wn, acc2);

    // ---- final epilogue: direct stores ----
#pragma unroll
    for (int nf = 0; nf < 4; ++nf) {
        const int col = wn * 64 + nf * 16 + (l & 15);
        const float g = g_out[col], bb = b_out[col];
#pragma unroll
        for (int mf = 0; mf < 2; ++mf)
#pragma unroll
            for (int r = 0; r < 4; ++r) {
                const int p = pix0 + wm * 32 + mf * 16 + (l >> 4) * 4 + r;
                outp[(size_t)p * 256 + col] = leaky(acc2[mf][nf][r] * g + bb, 0.1f);
            }
    }
}

// ---------------------------------------------------------------------------
// Launch
// ---------------------------------------------------------------------------
extern "C" void kernel_launch(void* const* d_in, const int* in_sizes, int n_in,
                              void* d_out, int out_size, void* d_ws, size_t ws_size,
                              hipStream_t stream)
{
    const float* inputs  = (const float*)d_in[0];
    const float* style   = (const float*)d_in[1];
    const float* W_dense = (const float*)d_in[2];
    const float* Wq_c = (const float*)d_in[3];
    const float* gq_c = (const float*)d_in[4];
    const float* bq_c = (const float*)d_in[5];
    const float* Wk_c = (const float*)d_in[6];
    const float* gk_c = (const float*)d_in[7];
    const float* bk_c = (const float*)d_in[8];
    const float* Wv_c = (const float*)d_in[9];
    const float* gv_c = (const float*)d_in[10];
    const float* bv_c = (const float*)d_in[11];
    // Wq_p/gq_p/bq_p (12..14) unused: qp-part is softmax-invariant
    const float* Wk_p = (const float*)d_in[15];
    const float* gk_p = (const float*)d_in[16];
    const float* bk_p = (const float*)d_in[17];
    const float* Wv_p = (const float*)d_in[18];
    const float* gv_p = (const float*)d_in[19];
    const float* bv_p = (const float*)d_in[20];
    const float* W_ch  = (const float*)d_in[21];
    const float* W_pos = (const float*)d_in[22];
    const float* W_out = (const float*)d_in[23];
    const float* g_out = (const float*)d_in[24];
    const float* b_out = (const float*)d_in[25];

    float* ws = (float*)d_ws;
    float* s1ws    = ws;                  //      4096
    float* qcws    = ws + 4096;           //      4096
    float* acq     = ws + 8192;           //      4096
    float* a_c     = ws + 12288;          //      4096
    float* partial = ws + 16384;          //    262144 (1024 x 256)
    float* logits  = ws + 278528;         //    262144 (65536 x 4) -> a_p in place
    __hip_bfloat16* in_bf = (__hip_bfloat16*)(ws + 540672);   // 65536x256 bf16 = 8388608 float-slots
    __hip_bfloat16* WT4   = (__hip_bfloat16*)(ws + 8929280);  // 4x256x256 bf16 [col][k]
    __hip_bfloat16* WoutT = (__hip_bfloat16*)(ws + 9060352);  // 256x512 bf16 [col][k]
    // total 9,125,888 floats = 36.5 MB

    kW_cvt<<<1408, 256, 0, stream>>>(Wk_c, Wv_c, Wk_p, Wv_p, W_out,
                                     WT4, WoutT, style, W_dense, s1ws);
    k1g<1><<<128, 256, 0, stream>>>(s1ws, Wq_c, gq_c, bq_c, qcws);
    k1g<2><<<128, 256, 0, stream>>>(qcws, W_ch, nullptr, nullptr, acq);

    kA<<<1024, 512, 0, stream>>>(inputs, in_bf, WT4, WT4 + 2 * 65536,
                                 gk_c, bk_c, gk_p, bk_p, W_pos, partial, logits);

    k2bc<<<80, 256, 0, stream>>>(partial, acq, W_ch, a_c, logits);

    kB<<<1024, 512, 0, stream>>>(in_bf, WT4 + 65536, WT4 + 3 * 65536, WoutT,
                                 gv_c, bv_c, gv_p, bv_p, a_c, logits,
                                 g_out, b_out, (float*)d_out);
}

// Round 18
// 134.308 us; speedup vs baseline: 3.7629x; 1.7153x over previous
//
#include <hip/hip_runtime.h>
#include <hip/hip_bf16.h>

#define PTOT  65536
#define SCALE 0.125f

typedef __attribute__((ext_vector_type(8))) short short8;
typedef __attribute__((ext_vector_type(4))) float f32x4;

__device__ __forceinline__ float leaky(float x, float a) { return x > 0.f ? x : a * x; }

__device__ __forceinline__ unsigned short f2bfbits(float f) {
    __hip_bfloat16 h = __float2bfloat16(f); unsigned short u;
    __builtin_memcpy(&u, &h, 2); return u;
}

__device__ __forceinline__ void gld16(const void* g, void* l) {
    __builtin_amdgcn_global_load_lds(
        (const __attribute__((address_space(1))) unsigned int*)g,
        (__attribute__((address_space(3))) unsigned int*)l, 16, 0, 0);
}

// ---------------------------------------------------------------------------
// MFMA / staging helpers, M=64 tile, 128B LDS rows, XOR swizzle slot=c^(row&7).
// ---------------------------------------------------------------------------
__device__ __forceinline__ void mfma_step64(const char* Aseg, const char* Bs,
                                            int l, int wm, int wn, f32x4 acc[2][4])
{
#pragma unroll
    for (int ks = 0; ks < 2; ++ks) {
        short8 af[2], bfr[4];
        const int c = ks * 4 + (l >> 4);
        const int sw = ((c ^ (l & 7)) << 4);
#pragma unroll
        for (int mf = 0; mf < 2; ++mf)
            af[mf] = *(const short8*)(Aseg + (wm * 32 + mf * 16 + (l & 15)) * 128 + sw);
#pragma unroll
        for (int nf = 0; nf < 4; ++nf)
            bfr[nf] = *(const short8*)(Bs + (wn * 64 + nf * 16 + (l & 15)) * 128 + sw);
#pragma unroll
        for (int mf = 0; mf < 2; ++mf)
#pragma unroll
            for (int nf = 0; nf < 4; ++nf)
                acc[mf][nf] = __builtin_amdgcn_mfma_f32_16x16x32_bf16(af[mf], bfr[nf], acc[mf][nf], 0, 0, 0);
    }
}

// Stage B tile: 256 cols x 64 k via global_load_lds, pre-swizzled source.
// NOTE R17: reading B directly from global (skipping LDS) fragments each
// wave-load into 16+ transactions (512B col stride) -> kB 68->162us. B staging
// through LDS is required for GEMM-style column-sliced consumption.
__device__ __forceinline__ void stageB(const __hip_bfloat16* Bt, int ldk, int k0,
                                       char* Bs, int w, int l, int cg)
{
#pragma unroll
    for (int pass = 0; pass < 4; ++pass) {
        const int col = w * 8 + (l >> 3) + pass * 64;
        gld16(Bt + (size_t)col * ldk + k0 + cg * 8, Bs + (w * 8 + pass * 64) * 128);
    }
}

// Stage A tile: 64 rows x 64 k (bf16 source, one pass of 512 threads).
__device__ __forceinline__ void stageA64(const __hip_bfloat16* Abf, int pix0, int k0,
                                         char* dst, int w, int l, int cg)
{
    const int row = w * 8 + (l >> 3);
    gld16(Abf + (size_t)(pix0 + row) * 256 + k0 + cg * 8, dst + w * 8 * 128);
}

// ---------------------------------------------------------------------------
// k1 GEMV stage body
// ---------------------------------------------------------------------------
template<int MODE>
__device__ __forceinline__ void k1_body(int bb, int t,
    const float* __restrict__ vin, const float* __restrict__ W,
    const float* __restrict__ g, const float* __restrict__ bv,
    float* __restrict__ vout, float* s0, float (*pr)[32])
{
    const int n = bb >> 3, c0 = (bb & 7) * 32;
    if (t < 256) s0[t] = vin[n * 256 + t];
    __syncthreads();
    const int kp = t >> 5, ci = t & 31, c = c0 + ci;
    float a = 0.f;
#pragma unroll 8
    for (int i = 0; i < 32; ++i) {
        const int k = kp * 32 + i;
        a += s0[k] * W[k * 256 + c];
    }
    pr[kp][ci] = a;
    __syncthreads();
    if (t < 32) {
        float s = 0.f;
#pragma unroll
        for (int q = 0; q < 8; ++q) s += pr[q][t];
        const int cc = c0 + t;
        if constexpr (MODE == 0)      vout[n * 256 + cc] = leaky(s, 0.3f);
        else if constexpr (MODE == 1) vout[n * 256 + cc] = leaky(s * g[cc] + bv[cc], 0.1f);
        else                          vout[n * 256 + cc] = 4096.f * s;
    }
}

template<int MODE>
__global__ __launch_bounds__(256) void k1g(
    const float* __restrict__ vin, const float* __restrict__ W,
    const float* __restrict__ g, const float* __restrict__ bv,
    float* __restrict__ vout)
{
    __shared__ float s0[256];
    __shared__ float pr[8][32];
    k1_body<MODE>(blockIdx.x, threadIdx.x, vin, W, g, bv, vout, s0, pr);
}

// ---------------------------------------------------------------------------
// Prep: blocks 0..1023 WT4 [w][col][k] bf16; 1024..1279 WoutT [col][512];
// 1280..1407 k1 stage0. (Input conversion lives inside kA.)
// ---------------------------------------------------------------------------
__global__ __launch_bounds__(256) void kW_cvt(
    const float* __restrict__ W0, const float* __restrict__ W1,
    const float* __restrict__ W2, const float* __restrict__ W3,
    const float* __restrict__ Wout,
    __hip_bfloat16* __restrict__ WT4, __hip_bfloat16* __restrict__ WoutT,
    const float* __restrict__ style, const float* __restrict__ W_dense,
    float* __restrict__ s1ws)
{
    __shared__ float s0[256];
    __shared__ float pr[8][32];
    const int b = blockIdx.x, t = threadIdx.x;
    if (b < 1024) {
        const int w = b >> 8, c = b & 255;
        const float* W = (w == 0) ? W0 : (w == 1) ? W1 : (w == 2) ? W2 : W3;
        WT4[((size_t)w * 256 + c) * 256 + t] = __float2bfloat16(W[t * 256 + c]);
    } else if (b < 1280) {
        const int c = b - 1024;
        WoutT[(size_t)c * 512 + t]       = __float2bfloat16(Wout[t * 256 + c]);
        WoutT[(size_t)c * 512 + t + 256] = __float2bfloat16(Wout[(t + 256) * 256 + c]);
    } else {
        k1_body<0>(b - 1280, t, style, W_dense, nullptr, nullptr, s1ws, s0, pr);
    }
}

// ---------------------------------------------------------------------------
// kA: merged kc+kp as ONE N=512 GEMM + in_bf producer. Per block: 64 pixels.
// Wave w owns cols w*64..w*64+63 of B~ = [WkcT | WkpT]; wave tile 64x64,
// acc[4][4], 8 K-32 steps off resident Afull. 8 ds_reads per 16 MFMAs.
// LDS 72KB -> 2 blocks/CU.
// NOTE R14: style-GEMV block fusion -> 120us straggler. NOTE R17: direct-B
// global reads -> uncoalesced, 2x slower. This config is the measured optimum.
// ---------------------------------------------------------------------------
__global__ __launch_bounds__(512, 4) void kA(
    const float* __restrict__ in, __hip_bfloat16* __restrict__ in_bf,
    const __hip_bfloat16* __restrict__ BkcT, const __hip_bfloat16* __restrict__ BkpT,
    const float* __restrict__ gkc, const float* __restrict__ bkc,
    const float* __restrict__ gkp, const float* __restrict__ bkp,
    const float* __restrict__ W_pos,
    float* __restrict__ partial, float* __restrict__ logits)
{
    __shared__ alignas(16) char smem[73728];
    char* Afull = smem;                        // [4 seg][64 row][128B] = 32KB
    char* Bs    = smem + 32768;                // [512 col][64B] = 32KB
    float* wpos_s = (float*)(smem + 65536);    // [256][4] = 4KB
    float* sc     = (float*)(smem + 69632);    // [64][4][4] = 4KB

    const int t = threadIdx.x, l = t & 63, w = t >> 6;   // w = 64-col group
    const int pix0 = blockIdx.x * 64;

    for (int e = t; e < 1024; e += 512) wpos_s[e] = W_pos[1024 + e]; // rows 256..511

    // stage full A tile from fp32 (row=t>>3, chunk c=t&7); also emit in_bf
    {
        const int row = t >> 3, c = t & 7;
#pragma unroll
        for (int seg = 0; seg < 4; ++seg) {
            const float* p = in + (size_t)(pix0 + row) * 256 + seg * 64 + c * 8;
            const float4 x0 = *(const float4*)p, x1 = *(const float4*)(p + 4);
            short8 v;
            v[0]=(short)f2bfbits(x0.x); v[1]=(short)f2bfbits(x0.y); v[2]=(short)f2bfbits(x0.z); v[3]=(short)f2bfbits(x0.w);
            v[4]=(short)f2bfbits(x1.x); v[5]=(short)f2bfbits(x1.y); v[6]=(short)f2bfbits(x1.z); v[7]=(short)f2bfbits(x1.w);
            *(short8*)(Afull + seg * 8192 + row * 128 + ((c ^ (row & 7)) << 4)) = v;
            *(short8*)(in_bf + (size_t)(pix0 + row) * 256 + seg * 64 + c * 8) = v;
        }
    }

    f32x4 acc[4][4];
#pragma unroll
    for (int i = 0; i < 4; ++i)
#pragma unroll
        for (int j = 0; j < 4; ++j) acc[i][j] = (f32x4)0.f;

    for (int s = 0; s < 8; ++s) {
        __syncthreads();                       // s=0: also covers Afull writes
        // stage B~ tile: 512 cols x 32 k, 64B rows, slot = chunk ^ ((col>>1)&3)
        {
            const int cg = (l & 3) ^ ((l >> 3) & 3);
#pragma unroll
            for (int p = 0; p < 4; ++p) {
                const int col = w * 16 + (l >> 2) + p * 128;
                const __hip_bfloat16* src = (p < 2)
                    ? BkcT + (size_t)col * 256
                    : BkpT + (size_t)(col - 256) * 256;
                gld16(src + s * 32 + cg * 8, Bs + (size_t)(w * 16 + p * 128) * 64);
            }
        }
        __syncthreads();
        // K-32 MFMA group: 4mf x 4nf
        {
            const int c8 = (s & 1) * 4 + (l >> 4);
            const char* Aseg = Afull + (s >> 1) * 8192;
            short8 af[4], bfr[4];
#pragma unroll
            for (int mf = 0; mf < 4; ++mf) {
                const int row = mf * 16 + (l & 15);
                af[mf] = *(const short8*)(Aseg + row * 128 + ((c8 ^ (row & 7)) << 4));
            }
#pragma unroll
            for (int nf = 0; nf < 4; ++nf) {
                const int brow = w * 64 + nf * 16 + (l & 15);
                bfr[nf] = *(const short8*)(Bs + brow * 64 + (((l >> 4) ^ ((brow >> 1) & 3)) << 4));
            }
#pragma unroll
            for (int mf = 0; mf < 4; ++mf)
#pragma unroll
                for (int nf = 0; nf < 4; ++nf)
                    acc[mf][nf] = __builtin_amdgcn_mfma_f32_16x16x32_bf16(af[mf], bfr[nf], acc[mf][nf], 0, 0, 0);
        }
    }

    if (w < 4) {
        // ---- kc epilogue: column sums over all 64 rows (in-wave) ----
#pragma unroll
        for (int nf = 0; nf < 4; ++nf) {
            const int col = w * 64 + nf * 16 + (l & 15);
            const float g = gkc[col], bb = bkc[col];
            float cs = 0.f;
#pragma unroll
            for (int mf = 0; mf < 4; ++mf)
#pragma unroll
                for (int r = 0; r < 4; ++r) cs += leaky(acc[mf][nf][r] * g + bb, 0.1f);
            cs += __shfl_xor(cs, 16);
            cs += __shfl_xor(cs, 32);
            if (l < 16) partial[(size_t)blockIdx.x * 256 + col] = cs;
        }
    } else {
        // ---- kp epilogue: pos logits; kp-col = (w-4)*64 + nf*16 + (l&15) ----
#pragma unroll
        for (int mf = 0; mf < 4; ++mf)
#pragma unroll
            for (int r = 0; r < 4; ++r) {
                const int row = mf * 16 + (l >> 4) * 4 + r;
                float pm0 = 0.f, pm1 = 0.f, pm2 = 0.f, pm3 = 0.f;
#pragma unroll
                for (int nf = 0; nf < 4; ++nf) {
                    const int kcol = (w - 4) * 64 + nf * 16 + (l & 15);
                    const float g = gkp[kcol], bb = bkp[kcol];
                    const float v = leaky(acc[mf][nf][r] * g + bb, 0.1f);
                    pm0 += v * wpos_s[kcol * 4 + 0];
                    pm1 += v * wpos_s[kcol * 4 + 1];
                    pm2 += v * wpos_s[kcol * 4 + 2];
                    pm3 += v * wpos_s[kcol * 4 + 3];
                }
#pragma unroll
                for (int mask = 1; mask <= 8; mask <<= 1) {
                    pm0 += __shfl_xor(pm0, mask);
                    pm1 += __shfl_xor(pm1, mask);
                    pm2 += __shfl_xor(pm2, mask);
                    pm3 += __shfl_xor(pm3, mask);
                }
                if ((l & 15) == 0) {
                    float* sp = &sc[row * 16 + (w - 4)];
                    sp[0] = pm0; sp[4] = pm1; sp[8] = pm2; sp[12] = pm3;
                }
            }
    }
    __syncthreads();
    if (t < 256) {
        const int row = t >> 2, m = t & 3;
        const float sum = sc[row * 16 + m * 4 + 0] + sc[row * 16 + m * 4 + 1]
                        + sc[row * 16 + m * 4 + 2] + sc[row * 16 + m * 4 + 3];
        logits[(size_t)(pix0 + row) * 4 + m] = SCALE * sum;
    }
}

// ---------------------------------------------------------------------------
// Fused softmax kernel: blocks 0..15 channel softmax; 16..79 position softmax.
// ---------------------------------------------------------------------------
__global__ __launch_bounds__(256) void k2bc(
    const float* __restrict__ partial,   // [1024][256]
    const float* __restrict__ acq, const float* __restrict__ W_ch,
    float* __restrict__ a_c, float* __restrict__ lg)
{
    const int t = threadIdx.x;
    if (blockIdx.x < 16) {
        __shared__ float ks[256], lgs[256];
        const int n = blockIdx.x;
        float s = 0.f;
        for (int tt = 0; tt < 64; ++tt) s += partial[(size_t)(n * 64 + tt) * 256 + t];
        ks[t] = s;
        __syncthreads();
        float bot = 0.f;
        for (int d = 0; d < 256; ++d) bot += ks[d] * W_ch[(256 + d) * 256 + t];
        const float L = SCALE * (acq[n * 256 + t] + bot);
        lgs[t] = L;
        __syncthreads();
        const int nh = t & 3;
        float mx = -1e30f;
        for (int i = 0; i < 64; ++i) mx = fmaxf(mx, lgs[i * 4 + nh]);
        float sum = 0.f;
        for (int i = 0; i < 64; ++i) sum += __expf(lgs[i * 4 + nh] - mx);
        a_c[n * 256 + t] = __expf(L - mx) / sum;
    } else {
        __shared__ float r[256];
        const int bb = blockIdx.x - 16;
        const int n = bb >> 2, m = bb & 3;
        const int base = n * 4096;
        float v[16];
        float mx = -1e30f;
#pragma unroll
        for (int i = 0; i < 16; ++i) {
            v[i] = lg[(size_t)(base + i * 256 + t) * 4 + m];
            mx = fmaxf(mx, v[i]);
        }
        r[t] = mx; __syncthreads();
        for (int s = 128; s > 0; s >>= 1) { if (t < s) r[t] = fmaxf(r[t], r[t + s]); __syncthreads(); }
        mx = r[0]; __syncthreads();
        float sum = 0.f;
#pragma unroll
        for (int i = 0; i < 16; ++i) { v[i] = __expf(v[i] - mx); sum += v[i]; }
        r[t] = sum; __syncthreads();
        for (int s = 128; s > 0; s >>= 1) { if (t < s) r[t] += r[t + s]; __syncthreads(); }
        const float rinv = 1.f / r[0];
#pragma unroll
        for (int i = 0; i < 16; ++i) lg[(size_t)(base + i * 256 + t) * 4 + m] = v[i] * rinv;
    }
}

// ---------------------------------------------------------------------------
// kB: fused v-recompute + attention-scale + output GEMM, halves-inner V
// (R11/R13/R15-measured best: 68 us, MfmaUtil 19.3, FETCH 42MB).
// Per block 64 pixels.
//   phase V: per K-step {stage A once + Bvc; mfma->acc1c; stage Bvp; mfma->acc1p}
//   epilogue-c -> A2; phase Gc (4 steps); epilogue-p -> A2; phase Gp (4 steps)
// A fetched ONCE. LDS 74KB -> 2 blocks/CU.
// NOTE: R8 (K=32 dbuf), R12 (merged window), R9 (LDS-out epilogue), R16
// (launch-bounds 6 -> acc spill), R17 (direct-B global) all REGRESSED.
// ---------------------------------------------------------------------------
__global__ __launch_bounds__(512, 4) void kB(
    const __hip_bfloat16* __restrict__ Abf,
    const __hip_bfloat16* __restrict__ BvcT, const __hip_bfloat16* __restrict__ BvpT,
    const __hip_bfloat16* __restrict__ WoutT,
    const float* __restrict__ gvc, const float* __restrict__ bvc,
    const float* __restrict__ gvp, const float* __restrict__ bvp,
    const float* __restrict__ a_c, const float* __restrict__ apos,
    const float* __restrict__ g_out, const float* __restrict__ b_out,
    float* __restrict__ outp)
{
    __shared__ alignas(16) char smem[75776];
    char* As   = smem;                        // [64 row][128B] = 8KB
    char* Bs   = smem + 8192;                 // [256 col][128B] = 32KB
    char* A2   = smem + 40960;                // [4 seg][64 row][128B] = 32KB
    float* ac_s = (float*)(smem + 73728);     // [256]
    float* ap_s = (float*)(smem + 74752);     // [64][4]

    const int t = threadIdx.x, l = t & 63, w = t >> 6;
    const int wm = w >> 2, wn = w & 3;
    const int pix0 = blockIdx.x * 64;
    const int n = pix0 >> 12;
    const int cg = (l & 7) ^ ((l >> 3) & 7);

    if (t < 256) {
        ac_s[t] = a_c[n * 256 + t];
        ap_s[t] = apos[(size_t)pix0 * 4 + t];
    }

    f32x4 acc1c[2][4], acc1p[2][4], acc2[2][4];
#pragma unroll
    for (int i = 0; i < 2; ++i)
#pragma unroll
        for (int j = 0; j < 4; ++j) {
            acc1c[i][j] = (f32x4)0.f;
            acc1p[i][j] = (f32x4)0.f;
            acc2[i][j]  = (f32x4)0.f;
        }

    // ---- phase V: A staged once per step, both halves' B off it ----
    for (int s = 0; s < 4; ++s) {
        __syncthreads();                       // s=0: also covers ac_s/ap_s
        stageA64(Abf, pix0, s * 64, As, w, l, cg);
        stageB(BvcT, 256, s * 64, Bs, w, l, cg);
        __syncthreads();
        mfma_step64(As, Bs, l, wm, wn, acc1c);
        __syncthreads();                       // Bs reads done
        stageB(BvpT, 256, s * 64, Bs, w, l, cg);
        __syncthreads();
        mfma_step64(As, Bs, l, wm, wn, acc1p); // As still valid
    }

    // ---- epilogue c: BN+leaky, a_c scale, bf16 -> A2 (swizzled) ----
#pragma unroll
    for (int nf = 0; nf < 4; ++nf) {
        const int col = wn * 64 + nf * 16 + (l & 15);
        const float g = gvc[col], bb = bvc[col];
        const int c2 = (col & 63) >> 3, cb = (col & 7) * 2;
        const float sc_c = ac_s[col];
#pragma unroll
        for (int mf = 0; mf < 2; ++mf)
#pragma unroll
            for (int r = 0; r < 4; ++r) {
                const int row = wm * 32 + mf * 16 + (l >> 4) * 4 + r;
                float v = leaky(acc1c[mf][nf][r] * g + bb, 0.1f) * sc_c;
                *(unsigned short*)(A2 + wn * 8192 + row * 128
                                   + ((c2 ^ (row & 7)) << 4) + cb) = f2bfbits(v);
            }
    }
    // ---- phase Gc: acc2 += A2 @ WoutT[:, 0..255] ----
    for (int s = 0; s < 4; ++s) {
        __syncthreads();                       // s=0: A2 writes + V's Bs reads done
        stageB(WoutT, 512, s * 64, Bs, w, l, cg);
        __syncthreads();
        mfma_step64(A2 + s * 8192, Bs, l, wm, wn, acc2);
    }
    __syncthreads();                           // all A2(c) reads done
    // ---- epilogue p: BN+leaky, a_p scale, bf16 -> A2 (overwrite) ----
#pragma unroll
    for (int nf = 0; nf < 4; ++nf) {
        const int col = wn * 64 + nf * 16 + (l & 15);
        const float g = gvp[col], bb = bvp[col];
        const int c2 = (col & 63) >> 3, cb = (col & 7) * 2;
#pragma unroll
        for (int mf = 0; mf < 2; ++mf)
#pragma unroll
            for (int r = 0; r < 4; ++r) {
                const int row = wm * 32 + mf * 16 + (l >> 4) * 4 + r;
                float v = leaky(acc1p[mf][nf][r] * g + bb, 0.1f) * ap_s[row * 4 + wn];
                *(unsigned short*)(A2 + wn * 8192 + row * 128
                                   + ((c2 ^ (row & 7)) << 4) + cb) = f2bfbits(v);
            }
    }
    // ---- phase Gp: acc2 += A2 @ WoutT[:, 256..511] ----
    for (int s = 0; s < 4; ++s) {
        __syncthreads();                       // s=0: A2(p) writes + Gc's Bs reads
        stageB(WoutT, 512, 256 + s * 64, Bs, w, l, cg);
        __syncthreads();
        mfma_step64(A2 + s * 8192, Bs, l, wm, wn, acc2);
    }

    // ---- final epilogue: direct stores ----
#pragma unroll
    for (int nf = 0; nf < 4; ++nf) {
        const int col = wn * 64 + nf * 16 + (l & 15);
        const float g = g_out[col], bb = b_out[col];
#pragma unroll
        for (int mf = 0; mf < 2; ++mf)
#pragma unroll
            for (int r = 0; r < 4; ++r) {
                const int p = pix0 + wm * 32 + mf * 16 + (l >> 4) * 4 + r;
                outp[(size_t)p * 256 + col] = leaky(acc2[mf][nf][r] * g + bb, 0.1f);
            }
    }
}

// ---------------------------------------------------------------------------
// Launch
// ---------------------------------------------------------------------------
extern "C" void kernel_launch(void* const* d_in, const int* in_sizes, int n_in,
                              void* d_out, int out_size, void* d_ws, size_t ws_size,
                              hipStream_t stream)
{
    const float* inputs  = (const float*)d_in[0];
    const float* style   = (const float*)d_in[1];
    const float* W_dense = (const float*)d_in[2];
    const float* Wq_c = (const float*)d_in[3];
    const float* gq_c = (const float*)d_in[4];
    const float* bq_c = (const float*)d_in[5];
    const float* Wk_c = (const float*)d_in[6];
    const float* gk_c = (const float*)d_in[7];
    const float* bk_c = (const float*)d_in[8];
    const float* Wv_c = (const float*)d_in[9];
    const float* gv_c = (const float*)d_in[10];
    const float* bv_c = (const float*)d_in[11];
    // Wq_p/gq_p/bq_p (12..14) unused: qp-part is softmax-invariant
    const float* Wk_p = (const float*)d_in[15];
    const float* gk_p = (const float*)d_in[16];
    const float* bk_p = (const float*)d_in[17];
    const float* Wv_p = (const float*)d_in[18];
    const float* gv_p = (const float*)d_in[19];
    const float* bv_p = (const float*)d_in[20];
    const float* W_ch  = (const float*)d_in[21];
    const float* W_pos = (const float*)d_in[22];
    const float* W_out = (const float*)d_in[23];
    const float* g_out = (const float*)d_in[24];
    const float* b_out = (const float*)d_in[25];

    float* ws = (float*)d_ws;
    float* s1ws    = ws;                  //      4096
    float* qcws    = ws + 4096;           //      4096
    float* acq     = ws + 8192;           //      4096
    float* a_c     = ws + 12288;          //      4096
    float* partial = ws + 16384;          //    262144 (1024 x 256)
    float* logits  = ws + 278528;         //    262144 (65536 x 4) -> a_p in place
    __hip_bfloat16* in_bf = (__hip_bfloat16*)(ws + 540672);   // 65536x256 bf16 = 8388608 float-slots
    __hip_bfloat16* WT4   = (__hip_bfloat16*)(ws + 8929280);  // 4x256x256 bf16 [col][k]
    __hip_bfloat16* WoutT = (__hip_bfloat16*)(ws + 9060352);  // 256x512 bf16 [col][k]
    // total 9,125,888 floats = 36.5 MB

    kW_cvt<<<1408, 256, 0, stream>>>(Wk_c, Wv_c, Wk_p, Wv_p, W_out,
                                     WT4, WoutT, style, W_dense, s1ws);
    k1g<1><<<128, 256, 0, stream>>>(s1ws, Wq_c, gq_c, bq_c, qcws);
    k1g<2><<<128, 256, 0, stream>>>(qcws, W_ch, nullptr, nullptr, acq);

    kA<<<1024, 512, 0, stream>>>(inputs, in_bf, WT4, WT4 + 2 * 65536,
                                 gk_c, bk_c, gk_p, bk_p, W_pos, partial, logits);

    k2bc<<<80, 256, 0, stream>>>(partial, acq, W_ch, a_c, logits);

    kB<<<1024, 512, 0, stream>>>(in_bf, WT4 + 65536, WT4 + 3 * 65536, WoutT,
                                 gv_c, bv_c, gv_p, bv_p, a_c, logits,
                                 g_out, b_out, (float*)d_out);
}